// Round 7
// baseline (166.252 us; speedup 1.0000x reference)
//
#include <hip/hip_runtime.h>

typedef unsigned int uint32;
typedef unsigned long long uint64;
typedef unsigned short ushort_t;
typedef _Float16 h2_t __attribute__((ext_vector_type(2)));
typedef float  f32x2 __attribute__((ext_vector_type(2)));
typedef float  f32x4 __attribute__((ext_vector_type(4)));
typedef uint32 u32x2 __attribute__((ext_vector_type(2)));

#define KNEI 32
#define DIM 128
#define WPB 4            // waves per block
#define RPW 2            // rows per wave (A in regs, B prefetched via LDS)
#define WAVE_LDS 8192    // one 32x128 packed-16b tile per wave

enum { SRC_BF16 = 0, SRC_F16 = 1, SRC_F32 = 2 };

__device__ __forceinline__ float bflo(uint32 u) {
    union { uint32 u; float f; } c; c.u = u << 16; return c.f;
}
__device__ __forceinline__ float bfhi(uint32 u) {
    union { uint32 u; float f; } c; c.u = u & 0xffff0000u; return c.f;
}
__device__ __forceinline__ uint32 pack_bf16_rne(float a, float b) {
    union { float f; uint32 u; } x, y; x.f = a; y.f = b;
    uint32 ua = (x.u + 0x7fffu + ((x.u >> 16) & 1u)) >> 16;
    uint32 ub = (y.u + 0x7fffu + ((y.u >> 16) & 1u)) >> 16;
    return (ua & 0xffffu) | (ub << 16);
}
__device__ __forceinline__ uint32 pack_f16(float a, float b) {
    union { h2_t h; uint32 u; } c;
    c.h.x = (_Float16)a; c.h.y = (_Float16)b;
    return c.u;
}
__device__ __forceinline__ h2_t as_h2(uint32 u) {
    union { uint32 u; h2_t h; } c; c.u = u; return c.h;
}

// async global->LDS, 16B per lane; lds dest = uniform base + lane*16.
__device__ __forceinline__ void prefetch16(const void* g, void* l) {
    __builtin_amdgcn_global_load_lds(
        (const __attribute__((address_space(1))) void*)g,
        (__attribute__((address_space(3))) void*)l,
        16, 0, 0);
}

// h: bf16 iff bits 14..7 of every sampled dword look like a bf16 exponent.
__device__ __forceinline__ bool probe_bf16(const void* h, int lane) {
    const uint32 hs = ((const uint32*)h)[lane];
    const uint32 e  = (hs >> 7) & 0xFFu;
    const bool  tb  = (e >= 90u) && (e <= 140u);
    return (__ballot(tb) == ~0ull);
}

// 8-elem dot of one packed-16b quad against an[8].
template<int SRC>
__device__ __forceinline__ float dot8(const uint4 e, const float* an) {
    if constexpr (SRC == SRC_BF16) {
        return bflo(e.x) * an[0] + bfhi(e.x) * an[1]
             + bflo(e.y) * an[2] + bfhi(e.y) * an[3]
             + bflo(e.z) * an[4] + bfhi(e.z) * an[5]
             + bflo(e.w) * an[6] + bfhi(e.w) * an[7];
    } else {
        const h2_t e0 = as_h2(e.x), e1 = as_h2(e.y), e2 = as_h2(e.z), e3 = as_h2(e.w);
        const float t0 = fmaf((float)e0.x, an[0],
                         fmaf((float)e0.y, an[1],
                         fmaf((float)e1.x, an[2], (float)e1.y * an[3])));
        const float t1 = fmaf((float)e2.x, an[4],
                         fmaf((float)e2.y, an[5],
                         fmaf((float)e3.x, an[6], (float)e3.y * an[7])));
        return t0 + t1;
    }
}

// acc[0..7] += wk * e (packed 16-bit quad).
template<int SRC>
__device__ __forceinline__ void acc8(float* acc, float wk, const uint4 e) {
    if constexpr (SRC == SRC_BF16) {
        acc[0] = fmaf(wk, bflo(e.x), acc[0]);
        acc[1] = fmaf(wk, bfhi(e.x), acc[1]);
        acc[2] = fmaf(wk, bflo(e.y), acc[2]);
        acc[3] = fmaf(wk, bfhi(e.y), acc[3]);
        acc[4] = fmaf(wk, bflo(e.z), acc[4]);
        acc[5] = fmaf(wk, bfhi(e.z), acc[5]);
        acc[6] = fmaf(wk, bflo(e.w), acc[6]);
        acc[7] = fmaf(wk, bfhi(e.w), acc[7]);
    } else {
        const h2_t e0 = as_h2(e.x), e1 = as_h2(e.y), e2 = as_h2(e.z), e3 = as_h2(e.w);
        acc[0] = fmaf(wk, (float)e0.x, acc[0]);
        acc[1] = fmaf(wk, (float)e0.y, acc[1]);
        acc[2] = fmaf(wk, (float)e1.x, acc[2]);
        acc[3] = fmaf(wk, (float)e1.y, acc[3]);
        acc[4] = fmaf(wk, (float)e2.x, acc[4]);
        acc[5] = fmaf(wk, (float)e2.y, acc[5]);
        acc[6] = fmaf(wk, (float)e3.x, acc[6]);
        acc[7] = fmaf(wk, (float)e3.y, acc[7]);
    }
}

// Score + softmax + weighted-sum for ONE row (tile in ev[8]); returns this
// lane's 2 output dims [8c + 2*r4, +2) via reduce-scatter (no full butterfly).
template<int SRC>
__device__ __forceinline__ f32x2 process_row(
    const uint4* ev, const float* an, float base, int r4)
{
    float s[8];
    #pragma unroll
    for (int it = 0; it < 8; ++it) s[it] = dot8<SRC>(ev[it], an);
    #pragma unroll
    for (int off = 1; off <= 8; off <<= 1) {
        #pragma unroll
        for (int it = 0; it < 8; ++it)
            s[it] += __shfl_xor(s[it], off, 64);
    }
    #pragma unroll
    for (int it = 0; it < 8; ++it) {
        const float v = base + s[it];
        s[it] = (v > 0.f) ? v : 0.01f * v;     // leaky_relu
    }

    float m = fmaxf(fmaxf(fmaxf(s[0], s[1]), fmaxf(s[2], s[3])),
                    fmaxf(fmaxf(s[4], s[5]), fmaxf(s[6], s[7])));
    m = fmaxf(m, __shfl_xor(m, 16, 64));
    m = fmaxf(m, __shfl_xor(m, 32, 64));

    float w[8];
    #pragma unroll
    for (int it = 0; it < 8; ++it) w[it] = __expf(s[it] - m);
    float sum = ((w[0] + w[1]) + (w[2] + w[3])) + ((w[4] + w[5]) + (w[6] + w[7]));
    sum += __shfl_xor(sum, 16, 64);
    sum += __shfl_xor(sum, 32, 64);
    const float inv = 1.0f / sum;

    float acc[8] = {0.f, 0.f, 0.f, 0.f, 0.f, 0.f, 0.f, 0.f};
    #pragma unroll
    for (int it = 0; it < 8; ++it)
        acc8<SRC>(acc, w[it] * inv, ev[it]);

    // reduce-scatter across r4 groups (verified in R6):
    const bool b1 = (r4 & 2) != 0;
    const bool b0 = (r4 & 1) != 0;
    float t[4];
    #pragma unroll
    for (int j = 0; j < 4; ++j) {
        const float keep = b1 ? acc[4 + j] : acc[j];
        const float send = b1 ? acc[j]     : acc[4 + j];
        t[j] = keep + __shfl_xor(send, 32, 64);
    }
    f32x2 o;
    {
        const float k0 = b0 ? t[2] : t[0];
        const float s0 = b0 ? t[0] : t[2];
        o.x = k0 + __shfl_xor(s0, 16, 64);
        const float k1 = b0 ? t[3] : t[1];
        const float s1 = b0 ? t[1] : t[3];
        o.y = k1 + __shfl_xor(s1, 16, 64);
    }
    return o;
}

// Two rows per wave. Row A gathered to registers; row B streamed global->LDS
// (no VGPR backing, cannot be sunk by the compiler) while A computes.
template<int SRC>
__device__ __forceinline__ void run_two(
    const void* __restrict__ hsv, const void* __restrict__ hrv,
    const void* __restrict__ attv, void* __restrict__ outv,
    const void* __restrict__ neiv, bool i64, int Mrows,
    size_t n0, bool valid2, int lane, char* wbase)
{
    constexpr bool F32 = (SRC != SRC_BF16);
    const int r4 = lane >> 4;
    const int c  = lane & 15;

    // 1) nei indices first (gathers depend on them); lanes 0..31 -> A, 32..63 -> B
    const size_t ebase = n0 * KNEI;
    const int esel = valid2 ? lane : (lane & 31);
    int idxv;
    if (i64) idxv = (int)__builtin_nontemporal_load((const long long*)neiv + ebase + esel);
    else     idxv = __builtin_nontemporal_load((const int*)neiv + ebase + esel);
    idxv = min(max(idxv, 0), Mrows - 1);            // OOB armor

    // 2) base-score operand loads (independent; fill the nei-wait shadow)
    const int r2 = lane >> 5, l5 = lane & 31;
    const size_t brow = n0 + (valid2 ? (size_t)r2 : 0);
    float hb[4], ab[4];
    if (F32) {
        const f32x4 hp = __builtin_nontemporal_load(
            (const f32x4*)((const float*)hrv + brow * DIM) + l5);
        const f32x4 ap = *((const f32x4*)attv + l5);
        hb[0] = hp.x; hb[1] = hp.y; hb[2] = hp.z; hb[3] = hp.w;
        ab[0] = ap.x; ab[1] = ap.y; ab[2] = ap.z; ab[3] = ap.w;
    } else {
        const u32x2 hu = __builtin_nontemporal_load(
            (const u32x2*)((const ushort_t*)hrv + brow * DIM) + l5);
        const u32x2 au = *((const u32x2*)attv + l5);
        hb[0] = bflo(hu.x); hb[1] = bfhi(hu.x); hb[2] = bflo(hu.y); hb[3] = bfhi(hu.y);
        ab[0] = bflo(au.x); ab[1] = bfhi(au.x); ab[2] = bflo(au.y); ab[3] = bfhi(au.y);
    }

    // 3) att_nei chunk for dims [8c, 8c+8)
    float an[8];
    if (F32) {
        const float4* ap = (const float4*)((const float*)attv + DIM + c * 8);
        const float4 p0 = ap[0], p1 = ap[1];
        an[0] = p0.x; an[1] = p0.y; an[2] = p0.z; an[3] = p0.w;
        an[4] = p1.x; an[5] = p1.y; an[6] = p1.z; an[7] = p1.w;
    } else {
        const uint4 au = *((const uint4*)((const ushort_t*)attv + DIM) + c);
        an[0] = bflo(au.x); an[1] = bfhi(au.x); an[2] = bflo(au.y); an[3] = bfhi(au.y);
        an[4] = bflo(au.z); an[5] = bfhi(au.z); an[6] = bflo(au.w); an[7] = bfhi(au.w);
    }

    // 4) distribute row indices
    int rows_a[8], rows_b[8];
    #pragma unroll
    for (int it = 0; it < 8; ++it) {
        rows_a[it] = __shfl(idxv, it * 4 + r4, 64);
        rows_b[it] = __shfl(idxv, 32 + it * 4 + r4, 64);
    }

    // 5) gather A into registers
    uint4 evA[8];
    #pragma unroll
    for (int it = 0; it < 8; ++it) {
        if constexpr (SRC == SRC_F32) {
            const float4* sp = (const float4*)hsv + ((size_t)rows_a[it] << 5) + c * 2;
            const float4 p0 = sp[0], p1 = sp[1];
            evA[it].x = pack_f16(p0.x, p0.y);
            evA[it].y = pack_f16(p0.z, p0.w);
            evA[it].z = pack_f16(p1.x, p1.y);
            evA[it].w = pack_f16(p1.z, p1.w);
        } else {
            evA[it] = *((const uint4*)hsv + ((size_t)rows_a[it] << 4) + c);
        }
    }

    // 6) prefetch B: 8 async global->LDS ops (issued here, land during A-compute)
    if constexpr (SRC != SRC_F32) {
        #pragma unroll
        for (int it = 0; it < 8; ++it)
            prefetch16((const uint4*)hsv + ((size_t)rows_b[it] << 4) + c,
                       wbase + it * 1024);
    }

    // 7) base-score reduce: lane covers dims [4*l5, +4) of row n0+r2
    float bsum = hb[0] * ab[0] + hb[1] * ab[1] + hb[2] * ab[2] + hb[3] * ab[3];
    #pragma unroll
    for (int off = 1; off <= 16; off <<= 1)
        bsum += __shfl_xor(bsum, off, 64);
    const float baseA = __shfl(bsum, 0, 64);
    const float baseB = __shfl(bsum, 32, 64);

    // 8) compute row A (prefetch B in flight underneath)
    const f32x2 oA = process_row<SRC>(evA, an, baseA, r4);

    // 9) row B
    f32x2 oB;
    if constexpr (SRC == SRC_F32) {
        uint4 evB[8];
        #pragma unroll
        for (int it = 0; it < 8; ++it) {
            const float4* sp = (const float4*)hsv + ((size_t)rows_b[it] << 5) + c * 2;
            const float4 p0 = sp[0], p1 = sp[1];
            evB[it].x = pack_f16(p0.x, p0.y);
            evB[it].y = pack_f16(p0.z, p0.w);
            evB[it].z = pack_f16(p1.x, p1.y);
            evB[it].w = pack_f16(p1.z, p1.w);
        }
        oB = process_row<SRC>(evB, an, baseB, r4);
    } else {
        // pin A-compute above the drain, then wait only for the prefetch
        __builtin_amdgcn_sched_barrier(0);
        asm volatile("s_waitcnt vmcnt(0)" ::: "memory");
        uint4 evB[8];
        #pragma unroll
        for (int it = 0; it < 8; ++it)
            evB[it] = *(const uint4*)(wbase + it * 1024 + lane * 16);
        oB = process_row<SRC>(evB, an, baseB, r4);
    }

    // 10) deferred coalesced NT stores (kept after the vmcnt fence)
    if (F32) {
        __builtin_nontemporal_store(oA, (f32x2*)((float*)outv + n0 * DIM) + c * 4 + r4);
        if (valid2)
            __builtin_nontemporal_store(oB, (f32x2*)((float*)outv + (n0 + 1) * DIM) + c * 4 + r4);
    } else {
        __builtin_nontemporal_store(pack_bf16_rne(oA.x, oA.y),
            (uint32*)((ushort_t*)outv + n0 * DIM) + c * 4 + r4);
        if (valid2)
            __builtin_nontemporal_store(pack_bf16_rne(oB.x, oB.y),
                (uint32*)((ushort_t*)outv + (n0 + 1) * DIM) + c * 4 + r4);
    }
}

// (256, 8): pin VGPR to the 64-granule so the 8-waves/SIMD cap is preserved
// (R6 lesson: VGPR 92 halves the wave-slot cap and regresses 25%).
__global__ __launch_bounds__(256, 8) void gat_kernel(
    const void* __restrict__ nei, const void* __restrict__ h,
    const void* __restrict__ h_refer, const void* __restrict__ att,
    void* __restrict__ out, const void* __restrict__ hf16,
    int N, int Mrows, int use_ws)
{
    __shared__ __align__(16) char smem[WPB * WAVE_LDS];
    const int tid  = threadIdx.x;
    const int lane = tid & 63;
    const int wave = tid >> 6;
    const size_t n0 = ((size_t)blockIdx.x * WPB + wave) * RPW;

    // dtype probes (wave-uniform)
    const bool is_bf16 = probe_bf16(h, lane);
    const uint32 nhi = ((const uint32*)nei)[2 * lane + 1];
    const bool  i64  = (__ballot(nhi == 0u) == ~0ull);

    if (n0 >= (size_t)N) return;   // whole wave exits; no barriers anywhere
    const bool valid2 = (n0 + 1 < (size_t)N);
    char* wbase = smem + wave * WAVE_LDS;   // wave-private LDS region

    if (is_bf16)     run_two<SRC_BF16>(h,    h_refer, att, out, nei, i64, Mrows, n0, valid2, lane, wbase);
    else if (use_ws) run_two<SRC_F16 >(hf16, h_refer, att, out, nei, i64, Mrows, n0, valid2, lane, wbase);
    else             run_two<SRC_F32 >(h,    h_refer, att, out, nei, i64, Mrows, n0, valid2, lane, wbase);
}

// h (f32) -> fp16 rows in workspace. Early-out if h is already bf16.
__global__ __launch_bounds__(256) void conv_kernel(
    const void* __restrict__ h, uint4* __restrict__ ws, long long ngroups)
{
    if (probe_bf16(h, threadIdx.x & 63)) return;
    const long long i = (long long)blockIdx.x * 256 + threadIdx.x;
    if (i >= ngroups) return;
    const f32x4* sp = (const f32x4*)h + i * 2;
    const f32x4 p0 = __builtin_nontemporal_load(sp);
    const f32x4 p1 = __builtin_nontemporal_load(sp + 1);
    uint4 o;
    o.x = pack_f16(p0.x, p0.y);
    o.y = pack_f16(p0.z, p0.w);
    o.z = pack_f16(p1.x, p1.y);
    o.w = pack_f16(p1.z, p1.w);
    ws[i] = o;
}

extern "C" void kernel_launch(void* const* d_in, const int* in_sizes, int n_in,
                              void* d_out, int out_size, void* d_ws, size_t ws_size,
                              hipStream_t stream) {
    const int N = out_size / DIM;          // authoritative: output rows
    const int M = in_sizes[1] / DIM;       // h rows (element count is dtype-independent)

    const size_t need = (size_t)M * DIM * sizeof(ushort_t);
    const int use_ws = (d_ws != nullptr && ws_size >= need) ? 1 : 0;

    if (use_ws) {
        const long long ngroups = (long long)M * (DIM / 8);   // 8 elems per thread
        dim3 cg((unsigned)((ngroups + 255) / 256)), cb(256);
        conv_kernel<<<cg, cb, 0, stream>>>(d_in[1], (uint4*)d_ws, ngroups);
    }

    const int rows_per_block = WPB * RPW;
    dim3 grid((N + rows_per_block - 1) / rows_per_block), block(64 * WPB);
    gat_kernel<<<grid, block, 0, stream>>>(d_in[0], d_in[1], d_in[2], d_in[3],
                                           d_out, d_ws, N, M, use_ws);
}